// Round 1
// baseline (21485.504 us; speedup 1.0000x reference)
//
#include <hip/hip_runtime.h>
#include <hip/hip_bf16.h>

#define T_STEPS 512
#define BATCH   64
#define DIN     512
#define DLAT    1024
#define KSLICE  768          // K rows per WG (global K-split by 2)
#define NGROUP  64           // j-groups of 16
#define NWG     128

typedef __bf16 bf16_t;
typedef __bf16 bf16x8 __attribute__((ext_vector_type(8)));
typedef __bf16 bf16x4 __attribute__((ext_vector_type(4)));
typedef float  f32x4  __attribute__((ext_vector_type(4)));

// ---- workspace layout (bytes) ----
#define XB_OFF     0u                      // bf16 x  [512][64][512]  = 33,554,432
#define HRING_OFF  33554432u               // bf16 h ring [2][64][1024] = 262,144
#define FLAG_OFF   33816576u               // int flag1[512][64] = 131,072
#define CNT_OFF    33947648u               // int cnt2[512] = 2,048
#define PART_OFF   33949696u               // float partial[64][4][4][64][4] = 1,048,576
#define ZERO_OFF   HRING_OFF
#define ZERO_BYTES (262144u + 131072u + 2048u)

// ---- LDS layout (dynamic, bytes) ----
#define WT_ELEMS   (64 * 776)              // [64 cols][768 + pad8] bf16
#define ACH_OFF_B  99328
#define CH_ELEMS   (64 * 136)              // [64 rows][128 + pad8] bf16 per buffer
#define GB_OFF_B   134144                  // float [4][64][17]
#define LDS_BYTES  151552

__global__ void xconv_kernel(const float* __restrict__ x, bf16_t* __restrict__ xb) {
    size_t i = ((size_t)blockIdx.x * 256 + threadIdx.x) * 4;
    const float4 v = *(const float4*)(x + i);
    bf16x4 o;
    o[0] = (bf16_t)v.x; o[1] = (bf16_t)v.y; o[2] = (bf16_t)v.z; o[3] = (bf16_t)v.w;
    *(bf16x4*)(xb + i) = o;
}

__device__ __forceinline__ const bf16_t* chunk_src(int ks, int ci, const bf16_t* xb_t,
                                                   const bf16_t* hprev, int row, int seg) {
    if (ks == 0) {
        if (ci < 4) return xb_t + row * DIN + ci * 128 + seg * 8;
        return hprev + row * DLAT + (ci - 4) * 128 + seg * 8;
    }
    return hprev + row * DLAT + 256 + ci * 128 + seg * 8;
}

__launch_bounds__(256, 1)
__global__ void lstm_main(const float* __restrict__ Wf, const float* __restrict__ Wi,
                          const float* __restrict__ Wo, const float* __restrict__ Wu,
                          const float* __restrict__ bfp, const float* __restrict__ bip,
                          const float* __restrict__ bop, const float* __restrict__ bup,
                          const bf16_t* __restrict__ xb,
                          bf16_t* __restrict__ hring,
                          float* __restrict__ partial,
                          int* __restrict__ flag1,
                          int* __restrict__ cnt2,
                          float* __restrict__ out) {
    extern __shared__ char lds[];
    bf16_t* Wt  = (bf16_t*)lds;                 // [64][776]
    bf16_t* Ach = (bf16_t*)(lds + ACH_OFF_B);   // [2][64][136]
    float*  gb  = (float*)(lds + GB_OFF_B);     // [4][64][17]

    const int tid  = threadIdx.x;
    const int wg   = blockIdx.x;
    const int g    = wg >> 1;        // colgroup 0..63
    const int ks   = wg & 1;         // K-slice
    const int wave = tid >> 6;       // = gate index 0..3 (f,i,o,u)
    const int lane = tid & 63;
    const int j0   = g * 16;
    const int kbase = ks * KSLICE;

    const float* Wgate[4] = {Wf, Wi, Wo, Wu};

    // ---- one-time: weights -> LDS (bf16, transposed [col][k], padded) ----
    {
        const int jj   = tid & 15;
        const int krow = tid >> 4;   // 0..15
        for (int gate = 0; gate < 4; ++gate) {
            const float* Wg = Wgate[gate];
            const int c = gate * 16 + jj;
            for (int k = krow; k < KSLICE; k += 16) {
                Wt[c * 776 + k] = (bf16_t)Wg[(kbase + k) * 1024 + j0 + jj];
            }
        }
    }
    __syncthreads();

    // per-thread bias registers (used by owners): thread -> b = tid>>2, jj0 = (tid&3)*4
    const int b_own = tid >> 2;
    const int jj0   = (tid & 3) * 4;
    float bre[4][4];
#pragma unroll
    for (int gt = 0; gt < 4; ++gt) {
        const float* bs = (gt == 0) ? bfp : (gt == 1) ? bip : (gt == 2) ? bop : bup;
#pragma unroll
        for (int i = 0; i < 4; ++i) bre[gt][i] = bs[j0 + jj0 + i];
    }
    float cst[4] = {0.f, 0.f, 0.f, 0.f};

    for (int t = 0; t < T_STEPS; ++t) {
        const bf16_t* xb_t  = xb + (size_t)t * (BATCH * DIN);
        const bf16_t* hprev = hring + (t & 1) * (BATCH * DLAT);
        bf16_t*       hnext = hring + ((t + 1) & 1) * (BATCH * DLAT);

        // ---- prologue: stage chunk 0 ----
#pragma unroll
        for (int it = 0; it < 4; ++it) {
            int idx = tid + it * 256;
            int row = idx >> 4, seg = idx & 15;
            bf16x8 v = *(const bf16x8*)chunk_src(ks, 0, xb_t, hprev, row, seg);
            *(bf16x8*)(Ach + row * 136 + seg * 8) = v;
        }

        f32x4 acc[4];
#pragma unroll
        for (int rf = 0; rf < 4; ++rf) acc[rf] = (f32x4){0.f, 0.f, 0.f, 0.f};

        for (int ci = 0; ci < 6; ++ci) {
            bf16x8 pf[4];
            if (ci < 5) {
#pragma unroll
                for (int it = 0; it < 4; ++it) {
                    int idx = tid + it * 256;
                    int row = idx >> 4, seg = idx & 15;
                    pf[it] = *(const bf16x8*)chunk_src(ks, ci + 1, xb_t, hprev, row, seg);
                }
            }
            __syncthreads();
            const bf16_t* Ab = Ach + (ci & 1) * CH_ELEMS;
#pragma unroll
            for (int kb = 0; kb < 4; ++kb) {
                const int koff = kb * 32 + (lane >> 4) * 8;
                bf16x8 bfr = *(const bf16x8*)(Wt + (wave * 16 + (lane & 15)) * 776 + ci * 128 + koff);
                bf16x8 a0 = *(const bf16x8*)(Ab + ((lane & 15) +  0) * 136 + koff);
                bf16x8 a1 = *(const bf16x8*)(Ab + ((lane & 15) + 16) * 136 + koff);
                bf16x8 a2 = *(const bf16x8*)(Ab + ((lane & 15) + 32) * 136 + koff);
                bf16x8 a3 = *(const bf16x8*)(Ab + ((lane & 15) + 48) * 136 + koff);
                acc[0] = __builtin_amdgcn_mfma_f32_16x16x32_bf16(a0, bfr, acc[0], 0, 0, 0);
                acc[1] = __builtin_amdgcn_mfma_f32_16x16x32_bf16(a1, bfr, acc[1], 0, 0, 0);
                acc[2] = __builtin_amdgcn_mfma_f32_16x16x32_bf16(a2, bfr, acc[2], 0, 0, 0);
                acc[3] = __builtin_amdgcn_mfma_f32_16x16x32_bf16(a3, bfr, acc[3], 0, 0, 0);
            }
            if (ci < 5) {
                const int dst = (ci + 1) & 1;
#pragma unroll
                for (int it = 0; it < 4; ++it) {
                    int idx = tid + it * 256;
                    int row = idx >> 4, seg = idx & 15;
                    *(bf16x8*)(Ach + dst * CH_ELEMS + row * 136 + seg * 8) = pf[it];
                }
            }
        }

        if (ks == 1) {
            // write partial [g][gate][rf][lane][4], then signal owner
            float* pb = partial + g * 4096;
#pragma unroll
            for (int rf = 0; rf < 4; ++rf) {
                *(f32x4*)(pb + ((wave * 4 + rf) * 64 + lane) * 4) = acc[rf];
            }
            __threadfence();
            __syncthreads();
            if (tid == 0)
                __hip_atomic_store(&flag1[t * NGROUP + g], 1, __ATOMIC_RELEASE, __HIP_MEMORY_SCOPE_AGENT);
        } else {
            // owner: wait for partner partial
            if (tid == 0) {
                while (__hip_atomic_load(&flag1[t * NGROUP + g], __ATOMIC_ACQUIRE, __HIP_MEMORY_SCOPE_AGENT) == 0) {
                    __builtin_amdgcn_s_sleep(1);
                }
            }
            __syncthreads();
            const float* pb = partial + g * 4096;
#pragma unroll
            for (int rf = 0; rf < 4; ++rf) {
                f32x4 p = *(const f32x4*)(pb + ((wave * 4 + rf) * 64 + lane) * 4);
                acc[rf] += p;
            }
            // exchange gates via LDS: gb[gate][b][jj] (pad 17)
#pragma unroll
            for (int rf = 0; rf < 4; ++rf) {
#pragma unroll
                for (int i = 0; i < 4; ++i) {
                    int b = rf * 16 + (lane >> 4) * 4 + i;
                    gb[(wave * 64 + b) * 17 + (lane & 15)] = acc[rf][i];
                }
            }
            __syncthreads();
            // elementwise: thread -> b_own, jj0..jj0+3
            float4 ho;
            bf16x4 hb;
#pragma unroll
            for (int i = 0; i < 4; ++i) {
                int jj = jj0 + i;
                float fv = gb[(0 * 64 + b_own) * 17 + jj] + bre[0][i];
                float iv = gb[(1 * 64 + b_own) * 17 + jj] + bre[1][i];
                float ov = gb[(2 * 64 + b_own) * 17 + jj] + bre[2][i];
                float uv = gb[(3 * 64 + b_own) * 17 + jj] + bre[3][i];
                float ft = 1.f / (1.f + __expf(-fv));
                float it = 1.f / (1.f + __expf(-iv));
                float ot = 1.f / (1.f + __expf(-ov));
                float ut = tanhf(uv);
                float cn = ft * cst[i] + it * ut;
                cst[i] = cn;
                float hv = ot * tanhf(cn);
                ((float*)&ho)[i] = hv;
                hb[i] = (bf16_t)hv;
            }
            *(float4*)(out + ((size_t)t * BATCH + b_own) * DLAT + j0 + jj0) = ho;
            *(bf16x4*)(hnext + b_own * DLAT + j0 + jj0) = hb;
            __threadfence();
            __syncthreads();
            if (tid == 0)
                __hip_atomic_fetch_add(&cnt2[t], 1, __ATOMIC_RELEASE, __HIP_MEMORY_SCOPE_AGENT);
        }

        // global step barrier: wait until all 64 owners have published h_t
        if (tid == 0) {
            while (__hip_atomic_load(&cnt2[t], __ATOMIC_ACQUIRE, __HIP_MEMORY_SCOPE_AGENT) < NGROUP) {
                __builtin_amdgcn_s_sleep(1);
            }
        }
        __syncthreads();
    }
}

extern "C" void kernel_launch(void* const* d_in, const int* in_sizes, int n_in,
                              void* d_out, int out_size, void* d_ws, size_t ws_size,
                              hipStream_t stream) {
    const float* x  = (const float*)d_in[0];
    const float* Wf = (const float*)d_in[1];
    const float* Wi = (const float*)d_in[2];
    const float* Wo = (const float*)d_in[3];
    const float* Wu = (const float*)d_in[4];
    const float* bf = (const float*)d_in[5];
    const float* bi = (const float*)d_in[6];
    const float* bo = (const float*)d_in[7];
    const float* bu = (const float*)d_in[8];
    float* out = (float*)d_out;

    char* ws = (char*)d_ws;
    bf16_t* xb     = (bf16_t*)(ws + XB_OFF);
    bf16_t* hring  = (bf16_t*)(ws + HRING_OFF);
    int*    flag1  = (int*)(ws + FLAG_OFF);
    int*    cnt2   = (int*)(ws + CNT_OFF);
    float*  part   = (float*)(ws + PART_OFF);

    // zero h ring + sync flags/counters (contiguous region)
    hipMemsetAsync(ws + ZERO_OFF, 0, ZERO_BYTES, stream);

    // convert x -> bf16
    xconv_kernel<<<16384, 256, 0, stream>>>(x, xb);

    // allow >64KB dynamic LDS
    static bool attr_set = false;
    hipFuncSetAttribute((const void*)lstm_main,
                        hipFuncAttributeMaxDynamicSharedMemorySize, LDS_BYTES);
    (void)attr_set;

    lstm_main<<<NWG, 256, LDS_BYTES, stream>>>(Wf, Wi, Wo, Wu, bf, bi, bo, bu,
                                               xb, hring, part, flag1, cnt2, out);
}

// Round 2
// 3741.473 us; speedup vs baseline: 5.7425x; 5.7425x over previous
//
#include <hip/hip_runtime.h>
#include <hip/hip_bf16.h>
#include <stdint.h>

#define T_STEPS 512
#define BATCH   64
#define DIN     512
#define DLAT    1024
#define NWG     128

typedef __bf16 bf16_t;
typedef __bf16 bf16x4 __attribute__((ext_vector_type(4)));
typedef __bf16 bf16x8 __attribute__((ext_vector_type(8)));
typedef float  f32x4  __attribute__((ext_vector_type(4)));

// ---- workspace layout (bytes) ----
#define XB_OFF    0u                        // bf16 x [512][64][512] = 33,554,432
#define HRING_OFF 33554432u                 // bf16 h ring [2][64][1024] = 262,144
#define CNT_OFF   (HRING_OFF + 262144u)     // int cnt[512] = 2,048
#define ZERO_BYTES (262144u + 2048u)

// ---- LDS layout (bytes) ----
#define WT_OFF_B   0                        // [32 cols][1536 k] bf16, XOR-swizzled = 98,304
#define RING_OFF_B 98304                    // 3 chunk slots x 16,384 ([64 rows][128 k] bf16 linear)
#define GB_OFF_B   147456                   // f32 [32][67] = 8,576
#define GB_PAD     67
#define LDS_BYTES  156032

__global__ void xconv_kernel(const float* __restrict__ x, bf16_t* __restrict__ xb) {
    size_t i = ((size_t)blockIdx.x * 256 + threadIdx.x) * 4;
    const float4 v = *(const float4*)(x + i);
    bf16x4 o;
    o[0] = (bf16_t)v.x; o[1] = (bf16_t)v.y; o[2] = (bf16_t)v.z; o[3] = (bf16_t)v.w;
    *(bf16x4*)(xb + i) = o;
}

__device__ __forceinline__ void gload_lds16(const void* src, void* dst) {
    typedef __attribute__((address_space(1))) void gvoid;
    typedef __attribute__((address_space(3))) void svoid;
    __builtin_amdgcn_global_load_lds((gvoid*)(void*)src, (svoid*)dst, 16, 0, 0);
}

// Stage z-chunk c ([64 rows][128 k] bf16, 16 KB) into ring slot c%3.
// LDS dest is linear; the XOR swizzle (byte ^= (row&7)<<4) is applied by
// pre-swizzling the per-lane GLOBAL source block index (m173 pattern).
__device__ __forceinline__ void stage_chunk(char* lds, int c,
                                            const bf16_t* xb_t, const bf16_t* hprev,
                                            int tid) {
    char* dstbase = lds + RING_OFF_B + (c % 3) * 16384;
    const int wv = tid >> 6;
#pragma unroll
    for (int it = 0; it < 4; ++it) {
        const int idx = it * 256 + tid;          // 0..1023 (16B blocks)
        const int row = idx >> 4;                // 0..63 batch row
        const int bg  = (idx & 15) ^ (row & 7);  // pre-swizzled source block
        const bf16_t* src = (c < 4) ? (xb_t + row * DIN + c * 128 + bg * 8)
                                    : (hprev + row * DLAT + (c - 4) * 128 + bg * 8);
        char* dst = dstbase + it * 4096 + wv * 1024;   // wave-uniform; HW adds lane*16
        gload_lds16((const void*)src, (void*)dst);
    }
}

__launch_bounds__(256, 1)
__global__ void lstm_main(const float* __restrict__ Wf, const float* __restrict__ Wi,
                          const float* __restrict__ Wo, const float* __restrict__ Wu,
                          const float* __restrict__ bfp, const float* __restrict__ bip,
                          const float* __restrict__ bop, const float* __restrict__ bup,
                          const bf16_t* __restrict__ xb,
                          bf16_t* __restrict__ hring,
                          int* __restrict__ cnt,
                          float* __restrict__ out) {
    extern __shared__ char lds[];
    float* gbf = (float*)(lds + GB_OFF_B);

    const int tid  = threadIdx.x;
    const int g    = blockIdx.x;      // 0..127: owns j = [g*8, g*8+8) x 4 gates
    const int wv   = tid >> 6;
    const int lane = tid & 63;
    const int j0   = g * 8;

    // ---- one-time: weights -> LDS bf16 [c=gate*8+jj][k], XOR-swizzled ----
    {
        const int c    = tid & 31;
        const int gate = c >> 3;
        const int jj   = c & 7;
        const float* Wg = (gate == 0) ? Wf : (gate == 1) ? Wi : (gate == 2) ? Wo : Wu;
        const int kb   = tid >> 5;    // 0..7
        for (int i = 0; i < 192; ++i) {
            const int k = kb + i * 8;
            const float w = Wg[(size_t)k * DLAT + j0 + jj];
            uint32_t addr = (uint32_t)(c * 3072 + k * 2);
            addr ^= (uint32_t)((c & 7) << 4);
            *(bf16_t*)(lds + WT_OFF_B + addr) = (bf16_t)w;
        }
    }

    // per-thread elementwise ownership: batch row bown, cols j0+jj2, j0+jj2+1
    const int bown = tid >> 2;
    const int jj2  = (tid & 3) * 2;
    float bias[4][2];
    {
        const float* bsrc[4] = {bfp, bip, bop, bup};
#pragma unroll
        for (int gt = 0; gt < 4; ++gt) {
            bias[gt][0] = bsrc[gt][j0 + jj2];
            bias[gt][1] = bsrc[gt][j0 + jj2 + 1];
        }
    }
    float cst[2] = {0.f, 0.f};
    __syncthreads();   // weights visible; pipeline not started yet so full drain is fine

    // prologue: issue x-chunks 0,1 of step 0
    stage_chunk(lds, 0, xb, hring, tid);
    stage_chunk(lds, 1, xb, hring, tid);

    for (int t = 0; t < T_STEPS; ++t) {
        const bf16_t* xb_t  = xb + (size_t)t * (BATCH * DIN);
        const bf16_t* hprev = hring + (size_t)(t & 1) * (BATCH * DLAT);
        bf16_t*       hnext = hring + (size_t)((t + 1) & 1) * (BATCH * DLAT);

        f32x4 acc[2];
        acc[0] = (f32x4){0.f, 0.f, 0.f, 0.f};
        acc[1] = (f32x4){0.f, 0.f, 0.f, 0.f};

        // ---- 12-chunk K loop, 3-slot ring, counted vmcnt, raw barriers ----
#pragma unroll
        for (int c = 0; c < 12; ++c) {
            if (c < 11) asm volatile("s_waitcnt vmcnt(4)" ::: "memory");
            else        asm volatile("s_waitcnt vmcnt(0)" ::: "memory");
            __builtin_amdgcn_s_barrier();
            asm volatile("" ::: "memory");
            const char* Ab = lds + RING_OFF_B + (c % 3) * 16384;
#pragma unroll
            for (int ks = 0; ks < 4; ++ks) {
                const uint32_t arow = (uint32_t)(wv * 16 + (lane & 15));
                uint32_t aoff = arow * 256 + (uint32_t)(ks * 64 + ((lane >> 4) * 16));
                aoff ^= (uint32_t)((lane & 7) << 4);
                const bf16x8 a = *(const bf16x8*)(Ab + aoff);
#pragma unroll
                for (int cf = 0; cf < 2; ++cf) {
                    const uint32_t col = (uint32_t)(cf * 16 + (lane & 15));
                    uint32_t boff = col * 3072 + (uint32_t)(((c * 4 + ks) * 64) + ((lane >> 4) * 16));
                    boff ^= (uint32_t)((lane & 7) << 4);
                    const bf16x8 b = *(const bf16x8*)(lds + WT_OFF_B + boff);
                    acc[cf] = __builtin_amdgcn_mfma_f32_16x16x32_bf16(a, b, acc[cf], 0, 0, 0);
                }
            }
            if (c < 10) stage_chunk(lds, c + 2, xb_t, hprev, tid);
        }

        // ---- exchange gates via LDS: gb[c][row] ----
#pragma unroll
        for (int cf = 0; cf < 2; ++cf)
#pragma unroll
            for (int i = 0; i < 4; ++i) {
                const int ccol = cf * 16 + (lane & 15);
                const int row  = wv * 16 + (lane >> 4) * 4 + i;
                gbf[ccol * GB_PAD + row] = acc[cf][i];
            }
        asm volatile("s_waitcnt lgkmcnt(0)" ::: "memory");
        __builtin_amdgcn_s_barrier();
        asm volatile("" ::: "memory");

        // ---- elementwise (fp32), c-state in registers ----
        float hv[2];
#pragma unroll
        for (int u = 0; u < 2; ++u) {
            const int jj = jj2 + u;
            const float fv = gbf[(0 * 8 + jj) * GB_PAD + bown] + bias[0][u];
            const float iv = gbf[(1 * 8 + jj) * GB_PAD + bown] + bias[1][u];
            const float ov = gbf[(2 * 8 + jj) * GB_PAD + bown] + bias[2][u];
            const float uv = gbf[(3 * 8 + jj) * GB_PAD + bown] + bias[3][u];
            const float ft = 1.f / (1.f + __expf(-fv));
            const float it = 1.f / (1.f + __expf(-iv));
            const float ot = 1.f / (1.f + __expf(-ov));
            const float ut = tanhf(uv);
            const float cn = ft * cst[u] + it * ut;
            cst[u] = cn;
            hv[u] = ot * tanhf(cn);
        }
        float2 o2; o2.x = hv[0]; o2.y = hv[1];
        *(float2*)(out + (size_t)t * (BATCH * DLAT) + (size_t)bown * DLAT + j0 + jj2) = o2;
        // h: agent-scope write-through (visible at coherence point, no L2 flush needed)
        const uint16_t h0b = __builtin_bit_cast(uint16_t, (bf16_t)hv[0]);
        const uint16_t h1b = __builtin_bit_cast(uint16_t, (bf16_t)hv[1]);
        const uint32_t hp  = ((uint32_t)h1b << 16) | (uint32_t)h0b;
        __hip_atomic_store((uint32_t*)(hnext + bown * DLAT + j0 + jj2), hp,
                           __ATOMIC_RELAXED, __HIP_MEMORY_SCOPE_AGENT);

        // drain own stores, then arrive
        asm volatile("s_waitcnt vmcnt(0)" ::: "memory");
        __builtin_amdgcn_s_barrier();
        asm volatile("" ::: "memory");
        if (tid == 0)
            __hip_atomic_fetch_add(&cnt[t], 1, __ATOMIC_RELAXED, __HIP_MEMORY_SCOPE_AGENT);

        // prefetch next step's x chunks during the wait (h not needed for them)
        if (t + 1 < T_STEPS) {
            const bf16_t* xb_n = xb + (size_t)(t + 1) * (BATCH * DIN);
            stage_chunk(lds, 0, xb_n, hnext, tid);
            stage_chunk(lds, 1, xb_n, hnext, tid);
        }

        // wait for all 128 WGs, one acquire fence (invalidate stale h in L1/L2)
        if (tid == 0) {
            while (__hip_atomic_load(&cnt[t], __ATOMIC_RELAXED, __HIP_MEMORY_SCOPE_AGENT) < NWG)
                __builtin_amdgcn_s_sleep(1);
            __builtin_amdgcn_fence(__ATOMIC_ACQUIRE, "agent");
        }
        __builtin_amdgcn_s_barrier();
        asm volatile("" ::: "memory");
    }
}

extern "C" void kernel_launch(void* const* d_in, const int* in_sizes, int n_in,
                              void* d_out, int out_size, void* d_ws, size_t ws_size,
                              hipStream_t stream) {
    const float* x  = (const float*)d_in[0];
    const float* Wf = (const float*)d_in[1];
    const float* Wi = (const float*)d_in[2];
    const float* Wo = (const float*)d_in[3];
    const float* Wu = (const float*)d_in[4];
    const float* bf = (const float*)d_in[5];
    const float* bi = (const float*)d_in[6];
    const float* bo = (const float*)d_in[7];
    const float* bu = (const float*)d_in[8];
    float* out = (float*)d_out;

    char* ws = (char*)d_ws;
    bf16_t* xb    = (bf16_t*)(ws + XB_OFF);
    bf16_t* hring = (bf16_t*)(ws + HRING_OFF);
    int*    cnt   = (int*)(ws + CNT_OFF);

    // zero h ring + step counters
    hipMemsetAsync(ws + HRING_OFF, 0, ZERO_BYTES, stream);

    // convert x -> bf16
    xconv_kernel<<<16384, 256, 0, stream>>>(x, xb);

    hipFuncSetAttribute((const void*)lstm_main,
                        hipFuncAttributeMaxDynamicSharedMemorySize, LDS_BYTES);

    lstm_main<<<NWG, 256, LDS_BYTES, stream>>>(Wf, Wi, Wo, Wu, bf, bi, bo, bu,
                                               xb, hring, cnt, out);
}